// Round 14
// baseline (373.988 us; speedup 1.0000x reference)
//
#include <hip/hip_runtime.h>

// QuantizedLinear: out[t][o] = sum_k x[t][k] * (w_q[o][k]-128)*scale[o] + bias[o]
// M=16, N=8192, K=8192. Memory-bound on w_q (256 MB int32, read once).
//
// R14 = R12 (64.6us: x via global_load_lds, raw s_barrier, packed f32 FMA)
// rebalanced for WAVE-LEVEL latency hiding: BLOCK=512 (8 waves), W_O=2,
// grid=512 -> still 2 blocks/CU but 16 waves/CU = 4 waves/SIMD (R12 had 2).
// R12's residual stall: per chunk, in-order vmcnt consumption of the
// youngest w-load drains the whole queue -> one loaded-HBM round trip
// (~9000cy under queuing) exposed per chunk per wave. Per-wave register
// depth is unbuyable (R9/R10/R13 all spilled: >=64 extra live VGPRs ->
// scratch); so overlap the drains across MORE waves instead. W_O=2 shrinks
// live set to ~90 VGPRs (acc2 32 + working) -- fits the 128/wave cap at
// 4 waves/SIMD without spill. Handoff soundness: stage loads are the 4
// OLDEST vmem ops of each chunk; explicit vmcnt(4) retires them before the
// barrier regardless of how the compiler schedules the FMA waits.

#define IN_F   8192
#define OUT_F  8192
#define NT     16
#define BLOCK  512
#define WAVES  8
#define W_O    2
#define CH_PER_BLOCK 16          // 8 waves * W_O
#define K_CHUNK 512
#define NCHUNK (IN_F / K_CHUNK)  // 16

typedef float f32x2 __attribute__((ext_vector_type(2)));

__global__ __launch_bounds__(BLOCK, 4)
void qlin_kernel(const float* __restrict__ x,     // [16][8192]
                 const int*   __restrict__ w_q,   // [8192][8192]
                 const float* __restrict__ scale, // [8192]
                 const float* __restrict__ bias,  // [8192]
                 float* __restrict__ out)         // [16][8192]
{
    __shared__ float xs[2][NT][K_CHUNK];          // 64 KB -> 2 blocks/CU

    const int tid  = threadIdx.x;
    const int lane = tid & 63;
    const int wave = tid >> 6;
    const int o_base = blockIdx.x * CH_PER_BLOCK + wave * W_O;

    const int* __restrict__ wr0 = w_q + (size_t)(o_base + 0) * IN_F;
    const int* __restrict__ wr1 = w_q + (size_t)(o_base + 1) * IN_F;

    // Stage x chunk c (32 KB = 16 rows x 2048 B) into LDS buf b.
    // 512 threads x 16 B = 8 KB/round -> 4 rounds. Each wave's 1 KB segment
    // stays inside one 2048 B row; LDS dest is wave-uniform base (+lane*16
    // added by HW), global src per-lane. (Verified structure from R12.)
#define STAGE(c, b)                                                          \
    {                                                                        \
        _Pragma("unroll")                                                    \
        for (int r = 0; r < 4; ++r) {                                        \
            const int f = r * 8192 + wave * 1024 + lane * 16;                \
            const int t = f >> 11;                                           \
            const char* g = (const char*)x + (size_t)t * 32768 +             \
                            (size_t)(c) * 2048 + (f & 2047);                 \
            char* l = (char*)(&xs[0][0][0]) + (b) * 32768 +                  \
                      r * 8192 + wave * 1024;                                \
            __builtin_amdgcn_global_load_lds(                                \
                (const __attribute__((address_space(1))) void*)g,            \
                (__attribute__((address_space(3))) void*)l, 16, 0, 0);       \
        }                                                                    \
    }

    f32x2 acc2[NT];   // acc2[t][e] = acc for rows o_base+e; 32 VGPRs
#pragma unroll
    for (int t = 0; t < NT; ++t) acc2[t] = (f32x2)0.0f;

    // prologue: stage chunk 0, full wait
    STAGE(0, 0)
    __builtin_amdgcn_sched_barrier(0);
    asm volatile("s_waitcnt vmcnt(0)" ::: "memory");
    __builtin_amdgcn_s_barrier();
    __builtin_amdgcn_sched_barrier(0);

#pragma unroll 1
    for (int c = 0; c < NCHUNK; ++c) {
        const int cur = c & 1;

        if (c + 1 < NCHUNK) STAGE(c + 1, cur ^ 1)   // oldest 4 vmem ops
        __builtin_amdgcn_sched_barrier(0);

        // ---- compute chunk c: 2 k-steps; w global (vmcnt), x LDS (lgkm) ----
#pragma unroll
        for (int ks = 0; ks < K_CHUNK / 256; ++ks) {
            const int kl = ks * 256 + lane * 4;     // within chunk
            const int kg = c * K_CHUNK + kl;        // global k
            const int4 w0 = *reinterpret_cast<const int4*>(wr0 + kg);
            const int4 w1 = *reinterpret_cast<const int4*>(wr1 + kg);

            f32x2 wf[4];   // wf[e] = { row0, row1 } at element e
            wf[0] = (f32x2){(float)(w0.x - 128), (float)(w1.x - 128)};
            wf[1] = (f32x2){(float)(w0.y - 128), (float)(w1.y - 128)};
            wf[2] = (f32x2){(float)(w0.z - 128), (float)(w1.z - 128)};
            wf[3] = (f32x2){(float)(w0.w - 128), (float)(w1.w - 128)};

#pragma unroll
            for (int t = 0; t < NT; ++t) {
                const float4 xv = *reinterpret_cast<const float4*>(
                    &xs[cur][t][kl]);
                acc2[t] += wf[0] * (f32x2){xv.x, xv.x};
                acc2[t] += wf[1] * (f32x2){xv.y, xv.y};
                acc2[t] += wf[2] * (f32x2){xv.z, xv.z};
                acc2[t] += wf[3] * (f32x2){xv.w, xv.w};
            }
        }

        // handoff: stage(c+1) are the 4 oldest vmem ops -> vmcnt(4) retires
        // them (keeps chunk-c w-loads irrelevant, they're consumed already);
        // no full drain beyond what FMA consumption already forced.
        __builtin_amdgcn_sched_barrier(0);
        if (c + 1 < NCHUNK) {
            asm volatile("s_waitcnt vmcnt(4)" ::: "memory");
        }
        asm volatile("s_waitcnt lgkmcnt(0)" ::: "memory");
        __builtin_amdgcn_s_barrier();
        __builtin_amdgcn_sched_barrier(0);
    }
#undef STAGE

    // ---- cross-lane reduction: 32 (t,j) values, 6-step butterfly each ----
    float myval = 0.0f;
#pragma unroll
    for (int t = 0; t < NT; ++t) {
#pragma unroll
        for (int j = 0; j < W_O; ++j) {
            float v = acc2[t][j];
#pragma unroll
            for (int off = 32; off > 0; off >>= 1)
                v += __shfl_xor(v, off, 64);
            if (lane == (t * W_O + j)) myval = v;
        }
    }

    // lane l (<32) -> t = l>>1, channel j = l&1
    if (lane < NT * W_O) {
        const int t_o = lane >> 1;
        const int o   = o_base + (lane & 1);
        out[(size_t)t_o * OUT_F + o] = myval * scale[o] + bias[o];
    }
}

extern "C" void kernel_launch(void* const* d_in, const int* in_sizes, int n_in,
                              void* d_out, int out_size, void* d_ws, size_t ws_size,
                              hipStream_t stream) {
    const float* x     = (const float*)d_in[0];
    const int*   w_q   = (const int*)d_in[1];
    const float* scale = (const float*)d_in[2];
    const float* bias  = (const float*)d_in[3];
    float*       out   = (float*)d_out;

    dim3 grid(OUT_F / CH_PER_BLOCK);   // 512 blocks -> 2/CU, 16 waves/CU
    dim3 block(BLOCK);
    qlin_kernel<<<grid, block, 0, stream>>>(x, w_q, scale, bias, out);
}

// Round 17
// 97.393 us; speedup vs baseline: 3.8400x; 3.8400x over previous
//
#include <hip/hip_runtime.h>

// QuantizedLinear: out[t][o] = sum_k x[t][k] * (w_q[o][k]-128)*scale[o] + bias[o]
// M=16, N=8192, K=8192. Memory-bound on w_q (256 MB int32, read once).
//
// R15: stage-x-once + barrier-free consume-older w-pipeline.
// R12 (64.6us, best) drains the vmcnt queue every chunk (FMAs consume
// same-chunk w-loads -> in-flight drops to 0, full loaded-HBM latency
// re-paid per chunk). Here each block owns a K-slice of 1024: x-slice
// (64 KB) staged to LDS once via global_load_lds + ONE barrier, then 4
// statically-unrolled k-steps where step ks+1's w-loads are issued BEFORE
// step ks's FMAs: in-order vmcnt waiting on ks's (older) loads leaves
// ks+1's flying -> pipeline never drains, no barriers in the loop.
// Split-K: 8 slices -> raw partials in d_ws (4 MB) + reduce kernel
// (scale/bias applied there); atomicAdd fallback if ws too small.
// VGPR discipline (R10/R11/R13/R14 lesson): launch_bounds(256,2) is the
// ONLY proven-sane allocator config; live set ~105 regs (acc2 32 + two
// 4xint4 w-buffers 32 + addr/misc) fits the 128 bucket, no spill.
// (Resubmitted unchanged after round-15 and round-16 infra failures.)

#define IN_F   8192
#define OUT_F  8192
#define NT     16
#define BLOCK  256
#define W_O    4
#define CH_PER_BLOCK 16          // 4 waves * W_O
#define K_SLICE 1024
#define NSLICE (IN_F / K_SLICE)  // 8

typedef float f32x2 __attribute__((ext_vector_type(2)));

template <bool ATOMIC>
__global__ __launch_bounds__(BLOCK, 2)
void qlin_main(const float* __restrict__ x,      // [16][8192]
               const int*   __restrict__ w_q,    // [8192][8192]
               const float* __restrict__ scale,  // [8192]
               float*       __restrict__ dst)    // ws [8][16][8192] or out
{
    __shared__ float xs[NT][K_SLICE];            // 64 KB -> 2 blocks/CU

    const int tid   = threadIdx.x;
    const int lane  = tid & 63;
    const int wave  = tid >> 6;
    const int slice = blockIdx.y;
    const int ks0   = slice * K_SLICE;
    const int o_base = blockIdx.x * CH_PER_BLOCK + wave * W_O;

    const int* __restrict__ wr0 = w_q + (size_t)(o_base + 0) * IN_F + ks0;
    const int* __restrict__ wr1 = w_q + (size_t)(o_base + 1) * IN_F + ks0;
    const int* __restrict__ wr2 = w_q + (size_t)(o_base + 2) * IN_F + ks0;
    const int* __restrict__ wr3 = w_q + (size_t)(o_base + 3) * IN_F + ks0;

    f32x2 acc2[NT][2];   // acc2[t][j2][e] = acc[t][j2*2+e]; 32 pairs
#pragma unroll
    for (int t = 0; t < NT; ++t) {
        acc2[t][0] = (f32x2)0.0f;
        acc2[t][1] = (f32x2)0.0f;
    }

    int4 bufA[4], bufB[4];       // two named w k-step buffers (static idx)

#define WLOAD(B, ks)                                                         \
    {                                                                        \
        B[0] = *reinterpret_cast<const int4*>(wr0 + (ks) * 256 + lane * 4);  \
        B[1] = *reinterpret_cast<const int4*>(wr1 + (ks) * 256 + lane * 4);  \
        B[2] = *reinterpret_cast<const int4*>(wr2 + (ks) * 256 + lane * 4);  \
        B[3] = *reinterpret_cast<const int4*>(wr3 + (ks) * 256 + lane * 4);  \
    }

#define FMA(B, ks)                                                           \
    {                                                                        \
        f32x2 wf[2][4];                                                      \
        wf[0][0] = (f32x2){(float)(B[0].x - 128), (float)(B[1].x - 128)};    \
        wf[0][1] = (f32x2){(float)(B[0].y - 128), (float)(B[1].y - 128)};    \
        wf[0][2] = (f32x2){(float)(B[0].z - 128), (float)(B[1].z - 128)};    \
        wf[0][3] = (f32x2){(float)(B[0].w - 128), (float)(B[1].w - 128)};    \
        wf[1][0] = (f32x2){(float)(B[2].x - 128), (float)(B[3].x - 128)};    \
        wf[1][1] = (f32x2){(float)(B[2].y - 128), (float)(B[3].y - 128)};    \
        wf[1][2] = (f32x2){(float)(B[2].z - 128), (float)(B[3].z - 128)};    \
        wf[1][3] = (f32x2){(float)(B[2].w - 128), (float)(B[3].w - 128)};    \
        _Pragma("unroll")                                                    \
        for (int t = 0; t < NT; ++t) {                                       \
            const float4 xv = *reinterpret_cast<const float4*>(              \
                &xs[t][(ks) * 256 + lane * 4]);                              \
            acc2[t][0] += wf[0][0] * (f32x2){xv.x, xv.x};                    \
            acc2[t][1] += wf[1][0] * (f32x2){xv.x, xv.x};                    \
            acc2[t][0] += wf[0][1] * (f32x2){xv.y, xv.y};                    \
            acc2[t][1] += wf[1][1] * (f32x2){xv.y, xv.y};                    \
            acc2[t][0] += wf[0][2] * (f32x2){xv.z, xv.z};                    \
            acc2[t][1] += wf[1][2] * (f32x2){xv.z, xv.z};                    \
            acc2[t][0] += wf[0][3] * (f32x2){xv.w, xv.w};                    \
            acc2[t][1] += wf[1][3] * (f32x2){xv.w, xv.w};                    \
        }                                                                    \
    }

    // ---- prologue: w(0) first (retires during stage drain), then stage ----
    WLOAD(bufA, 0)
    __builtin_amdgcn_sched_barrier(0);
    // stage x slice: 16 rounds, one 4 KB row per round (256 thr x 16 B);
    // LDS dest wave-uniform base + lane*16 (HW), global src lane-linear.
#pragma unroll
    for (int r = 0; r < NT; ++r) {
        const char* g = (const char*)x + (size_t)r * (IN_F * 4) + ks0 * 4 +
                        wave * 1024 + lane * 16;
        char* l = (char*)(&xs[0][0]) + r * 4096 + wave * 1024;
        __builtin_amdgcn_global_load_lds(
            (const __attribute__((address_space(1))) void*)g,
            (__attribute__((address_space(3))) void*)l, 16, 0, 0);
    }
    __builtin_amdgcn_sched_barrier(0);
    asm volatile("s_waitcnt vmcnt(0)" ::: "memory");   // stage (+w0) landed
    __builtin_amdgcn_s_barrier();
    __builtin_amdgcn_sched_barrier(0);

    // ---- 4 barrier-free k-steps, consume-older pipeline ----
    WLOAD(bufB, 1)                 // flies under FMA(bufA,0)
    __builtin_amdgcn_sched_barrier(0);
    FMA(bufA, 0)
    WLOAD(bufA, 2)
    __builtin_amdgcn_sched_barrier(0);
    FMA(bufB, 1)
    WLOAD(bufB, 3)
    __builtin_amdgcn_sched_barrier(0);
    FMA(bufA, 2)
    FMA(bufB, 3)

#undef WLOAD
#undef FMA

    // ---- cross-lane reduction: 64 (t,j) values, 6-step butterfly each ----
    float myval = 0.0f;
#pragma unroll
    for (int t = 0; t < NT; ++t) {
#pragma unroll
        for (int j = 0; j < W_O; ++j) {
            float v = acc2[t][j >> 1][j & 1];
#pragma unroll
            for (int off = 32; off > 0; off >>= 1)
                v += __shfl_xor(v, off, 64);
            if (lane == (t * W_O + j)) myval = v;
        }
    }

    // lane l -> (t = l>>2, channel j = l&3)
    const int t_o = lane >> 2;
    const int o   = o_base + (lane & 3);
    if (ATOMIC) {
        atomicAdd(&dst[(size_t)t_o * OUT_F + o], myval * scale[o]);
    } else {
        dst[((size_t)(slice * NT + t_o)) * OUT_F + o] = myval;  // raw partial
    }
}

__global__ __launch_bounds__(512)
void qlin_reduce(const float* __restrict__ ws, const float* __restrict__ scale,
                 const float* __restrict__ bias, float* __restrict__ out)
{
    const int idx = blockIdx.x * 512 + threadIdx.x;   // 0 .. 16*8192-1
    const int o = idx & (OUT_F - 1);
    float s = 0.0f;
#pragma unroll
    for (int sl = 0; sl < NSLICE; ++sl)
        s += ws[(size_t)sl * (NT * OUT_F) + idx];
    out[idx] = s * scale[o] + bias[o];
}

__global__ __launch_bounds__(512)
void qlin_init(const float* __restrict__ bias, float* __restrict__ out)
{
    const int idx = blockIdx.x * 512 + threadIdx.x;
    out[idx] = bias[idx & (OUT_F - 1)];
}

extern "C" void kernel_launch(void* const* d_in, const int* in_sizes, int n_in,
                              void* d_out, int out_size, void* d_ws, size_t ws_size,
                              hipStream_t stream) {
    const float* x     = (const float*)d_in[0];
    const int*   w_q   = (const int*)d_in[1];
    const float* scale = (const float*)d_in[2];
    const float* bias  = (const float*)d_in[3];
    float*       out   = (float*)d_out;

    const dim3 grid(OUT_F / CH_PER_BLOCK, NSLICE);   // 512 x 8 = 4096 blocks
    const dim3 block(BLOCK);
    const size_t ws_need = (size_t)NSLICE * NT * OUT_F * sizeof(float);  // 4 MB

    if (ws_size >= ws_need) {
        float* ws = (float*)d_ws;
        qlin_main<false><<<grid, block, 0, stream>>>(x, w_q, scale, ws);
        qlin_reduce<<<(NT * OUT_F) / 512, 512, 0, stream>>>(ws, scale, bias, out);
    } else {
        qlin_init<<<(NT * OUT_F) / 512, 512, 0, stream>>>(bias, out);
        qlin_main<true><<<grid, block, 0, stream>>>(x, w_q, scale, out);
    }
}

// Round 19
// 65.680 us; speedup vs baseline: 5.6941x; 1.4828x over previous
//
#include <hip/hip_runtime.h>

// QuantizedLinear: out[t][o] = sum_k x[t][k] * (w_q[o][k]-128)*scale[o] + bias[o]
// M=16, N=8192, K=8192. Memory-bound on w_q (256 MB int32, read once).
//
// R18 = R12 (64.6us best: x via global_load_lds, double-buffered, raw
// s_barrier with lgkm-only wait, packed f32x2 FMA) with DOUBLED WAVE
// RESIDENCY via LDS, not launch_bounds: K_CHUNK 512->256 (LDS 64->32 KB)
// and W_O 4->2 (grid 512->1024) -> 4 blocks/CU = 16 waves/CU (R12: 8).
// Allocator model (R10-R14): cap = 256/arg2; only (256,2)->128 is sane, so
// occupancy must come from usage (LDS/VGPR), never from launch_bounds.
// Live set ~70 VGPR (acc2 32 + wf 8 + w-bufs 8 + addr) -- well under 128.
// Monolithic full-K per block is settled (split-K lost twice: R8, R15).
// Handoff soundness: per chunk, the 4 stage loads are issued (pinned by
// sched_barrier) BEFORE the 2 w-loads; FMAs consume both w-loads, and
// in-order vmcnt retirement of a younger load implies the older stage
// loads retired -> barrier needs no vmcnt drain (vmcnt(2) kept as a
// cheap already-satisfied safeguard).
// (Resubmitted unchanged after round-18 infra failure.)

#define IN_F   8192
#define OUT_F  8192
#define NT     16
#define BLOCK  256
#define W_O    2
#define CH_PER_BLOCK 8           // 4 waves * W_O
#define K_CHUNK 256
#define NCHUNK (IN_F / K_CHUNK)  // 32

typedef float f32x2 __attribute__((ext_vector_type(2)));

__global__ __launch_bounds__(BLOCK, 2)
void qlin_kernel(const float* __restrict__ x,     // [16][8192]
                 const int*   __restrict__ w_q,   // [8192][8192]
                 const float* __restrict__ scale, // [8192]
                 const float* __restrict__ bias,  // [8192]
                 float* __restrict__ out)         // [16][8192]
{
    __shared__ float xs[2][NT][K_CHUNK];          // 32 KB -> 4 blocks/CU

    const int tid  = threadIdx.x;
    const int lane = tid & 63;
    const int wave = tid >> 6;
    const int o_base = blockIdx.x * CH_PER_BLOCK + wave * W_O;

    const int* __restrict__ wr0 = w_q + (size_t)(o_base + 0) * IN_F;
    const int* __restrict__ wr1 = w_q + (size_t)(o_base + 1) * IN_F;

    // Stage x chunk c (16 KB = 16 rows x 1024 B) into LDS buf b.
    // 4 rounds x 4 KB (256 thr x 16 B). Wave w in round r stages exactly
    // row r*4+w: global 16B/lane contiguous, LDS dest wave-uniform base
    // (+lane*16 by HW) -- linear, per global_load_lds contract.
#define STAGE(c, b)                                                          \
    {                                                                        \
        _Pragma("unroll")                                                    \
        for (int r = 0; r < 4; ++r) {                                        \
            const int row = r * 4 + wave;                                    \
            const char* g = (const char*)x + (size_t)row * (IN_F * 4) +      \
                            (size_t)(c) * 1024 + lane * 16;                  \
            char* l = (char*)(&xs[0][0][0]) + (b) * 16384 +                  \
                      row * 1024;                                            \
            __builtin_amdgcn_global_load_lds(                                \
                (const __attribute__((address_space(1))) void*)g,            \
                (__attribute__((address_space(3))) void*)l, 16, 0, 0);       \
        }                                                                    \
    }

    f32x2 acc2[NT];   // acc2[t][e] = acc for row o_base+e; 32 VGPRs
#pragma unroll
    for (int t = 0; t < NT; ++t) acc2[t] = (f32x2)0.0f;

    // prologue: stage chunk 0, full wait (nothing else in flight yet)
    STAGE(0, 0)
    __builtin_amdgcn_sched_barrier(0);
    asm volatile("s_waitcnt vmcnt(0)" ::: "memory");
    __builtin_amdgcn_s_barrier();
    __builtin_amdgcn_sched_barrier(0);

#pragma unroll 1
    for (int c = 0; c < NCHUNK; ++c) {
        const int cur = c & 1;

        if (c + 1 < NCHUNK) STAGE(c + 1, cur ^ 1)   // 4 oldest vmem ops
        __builtin_amdgcn_sched_barrier(0);

        // ---- compute chunk c: one 256-wide k-step ----
        {
            const int kl = lane * 4;                // within chunk
            const int kg = c * K_CHUNK + kl;        // global k
            const int4 w0 = *reinterpret_cast<const int4*>(wr0 + kg);
            const int4 w1 = *reinterpret_cast<const int4*>(wr1 + kg);

            f32x2 wf[4];   // wf[e] = { row0, row1 } at element e
            wf[0] = (f32x2){(float)(w0.x - 128), (float)(w1.x - 128)};
            wf[1] = (f32x2){(float)(w0.y - 128), (float)(w1.y - 128)};
            wf[2] = (f32x2){(float)(w0.z - 128), (float)(w1.z - 128)};
            wf[3] = (f32x2){(float)(w0.w - 128), (float)(w1.w - 128)};

#pragma unroll
            for (int t = 0; t < NT; ++t) {
                const float4 xv = *reinterpret_cast<const float4*>(
                    &xs[cur][t][kl]);
                acc2[t] += wf[0] * (f32x2){xv.x, xv.x};
                acc2[t] += wf[1] * (f32x2){xv.y, xv.y};
                acc2[t] += wf[2] * (f32x2){xv.z, xv.z};
                acc2[t] += wf[3] * (f32x2){xv.w, xv.w};
            }
        }

        // handoff: FMAs consumed w-loads (younger than the 4 stage loads),
        // so stage already retired; vmcnt(2) is a free safeguard. lgkm(0)
        // covers ds_reads. NO vmcnt(0) drain -- that was R1's killer.
        __builtin_amdgcn_sched_barrier(0);
        if (c + 1 < NCHUNK) {
            asm volatile("s_waitcnt vmcnt(2)" ::: "memory");
            asm volatile("s_waitcnt lgkmcnt(0)" ::: "memory");
            __builtin_amdgcn_s_barrier();
            __builtin_amdgcn_sched_barrier(0);
        }
    }
#undef STAGE

    // ---- cross-lane reduction: 32 (t,j) values, 6-step butterfly each ----
    float myval = 0.0f;
#pragma unroll
    for (int t = 0; t < NT; ++t) {
#pragma unroll
        for (int j = 0; j < W_O; ++j) {
            float v = acc2[t][j];
#pragma unroll
            for (int off = 32; off > 0; off >>= 1)
                v += __shfl_xor(v, off, 64);
            if (lane == (t * W_O + j)) myval = v;
        }
    }

    // lane l (<32) -> t = l>>1, channel j = l&1
    if (lane < NT * W_O) {
        const int t_o = lane >> 1;
        const int o   = o_base + (lane & 1);
        out[(size_t)t_o * OUT_F + o] = myval * scale[o] + bias[o];
    }
}

extern "C" void kernel_launch(void* const* d_in, const int* in_sizes, int n_in,
                              void* d_out, int out_size, void* d_ws, size_t ws_size,
                              hipStream_t stream) {
    const float* x     = (const float*)d_in[0];
    const int*   w_q   = (const int*)d_in[1];
    const float* scale = (const float*)d_in[2];
    const float* bias  = (const float*)d_in[3];
    float*       out   = (float*)d_out;

    dim3 grid(OUT_F / CH_PER_BLOCK);   // 1024 blocks -> 4/CU, 16 waves/CU
    dim3 block(BLOCK);
    qlin_kernel<<<grid, block, 0, stream>>>(x, w_q, scale, bias, out);
}